// Round 1
// baseline (451.334 us; speedup 1.0000x reference)
//
#include <hip/hip_runtime.h>
#include <hip/hip_bf16.h>
#include <math.h>
#include <stdint.h>

#define N_NODES 100000
#define N_EDGES 1600000
#define ET (N_EDGES + N_NODES)   // 1,700,000 edges incl. self-loops
#define FDIM 128
#define NK 16
#define EPS 1e-5f
#define SLOPE 0.2f

typedef __attribute__((ext_vector_type(8))) short bf16x8;
typedef __attribute__((ext_vector_type(4))) float f32x4;
typedef __attribute__((ext_vector_type(2))) _Float16 h2;

__device__ inline unsigned pk_bf16(float a, float b) {
    float2 f; f.x = a; f.y = b;
    __hip_bfloat162 t = __float22bfloat162_rn(f);
    return *reinterpret_cast<unsigned*>(&t);
}
__device__ inline h2 as_h2(unsigned u) { return __builtin_bit_cast(h2, u); }
__device__ inline unsigned as_u(h2 v) { return __builtin_bit_cast(unsigned, v); }

// single-instruction lane swizzle (BitMode: src = ((lane&and)|or)^xor)
#define SWZ(X, P) __int_as_float(__builtin_amdgcn_ds_swizzle(__float_as_int(X), (P)))
// DPP lane permutes (VALU-pipe, no LDS latency)
#define DPPF(X, CTRL) __int_as_float(__builtin_amdgcn_mov_dpp(__float_as_int(X), (CTRL), 0xF, 0xF, true))
#define DX1(X) DPPF(X, 0xB1)    // quad_perm [1,0,3,2]  == xor 1
#define DX2(X) DPPF(X, 0x4E)    // quad_perm [2,3,0,1]  == xor 2
#define DR8(X) DPPF(X, 0x128)   // row_ror:8            == xor 8 within 16-row

// ---------------- CSR build: 2-phase bucket partition ----------------

#define NBKT 196
#define BSH 9                      // 512 nodes / bucket
#define BSTRIDE 10240              // staging stride (mean 8704, sigma 93 -> +16 sigma)
#define P1_EPT 8
#define P1_EPB (256 * P1_EPT)      // 2048 edges / block

__global__ __launch_bounds__(256) void part_kernel(const int* __restrict__ ei,
                                                   int* __restrict__ gcount,
                                                   int* __restrict__ staging) {
    __shared__ int hist[NBKT];
    __shared__ int lofs[NBKT];
    __shared__ int gbase[NBKT];
    __shared__ int s[256];
    __shared__ int spk[P1_EPB];
    __shared__ short sbk[P1_EPB];
    int t = threadIdx.x;
    if (t < NBKT) hist[t] = 0;
    __syncthreads();
    int e0 = blockIdx.x * P1_EPB + t;
    int pk[P1_EPT], bk[P1_EPT], rk[P1_EPT];
#pragma unroll
    for (int k = 0; k < P1_EPT; k++) {
        int e = e0 + k * 256;
        bk[k] = -1;
        if (e < ET) {
            int src, dst;
            if (e < N_EDGES) { src = ei[e]; dst = ei[N_EDGES + e]; }
            else             { src = dst = e - N_EDGES; }
            int b = dst >> BSH;
            pk[k] = (src << BSH) | (dst & 511);
            bk[k] = b;
            rk[k] = atomicAdd(&hist[b], 1);
        }
    }
    __syncthreads();
    int v = (t < NBKT) ? hist[t] : 0;
    s[t] = v;
    __syncthreads();
    for (int o = 1; o < 256; o <<= 1) {
        int add = (t >= o) ? s[t - o] : 0;
        __syncthreads();
        s[t] += add;
        __syncthreads();
    }
    if (t < NBKT) {
        lofs[t] = s[t] - v;                    // block-local exclusive offset
        gbase[t] = (v > 0) ? atomicAdd(&gcount[t], v) : 0;
    }
    __syncthreads();
#pragma unroll
    for (int k = 0; k < P1_EPT; k++) {
        if (bk[k] >= 0) {
            int idx = lofs[bk[k]] + rk[k];
            spk[idx] = pk[k];
            sbk[idx] = (short)bk[k];
        }
    }
    __syncthreads();
    int tot = lofs[NBKT - 1] + hist[NBKT - 1];
    for (int i = t; i < tot; i += 256) {
        int b = sbk[i];
        staging[b * BSTRIDE + gbase[b] + (i - lofs[b])] = spk[i];
    }
}

// bucket CSR with fused global bucket-base scan (replaces bscan_kernel)
__global__ __launch_bounds__(1024) void bucket_csr_kernel(
        const int* __restrict__ staging, const int* __restrict__ gcount,
        int* __restrict__ off, int* __restrict__ perm) {
    __shared__ int hist[512];
    __shared__ int scn[512];
    __shared__ int cur[512];
    __shared__ int gpre[256];
    int b = blockIdx.x;
    int t = threadIdx.x;
    if (t < 512) hist[t] = 0;
    if (t < 256) gpre[t] = (t < NBKT) ? gcount[t] : 0;
    __syncthreads();
    int sz = gcount[b];
    for (int k = t; k < sz; k += 1024)
        atomicAdd(&hist[staging[b * BSTRIDE + k] & 511], 1);
    __syncthreads();
    int v = (t < 512) ? hist[t] : 0;
    if (t < 512) scn[t] = v;
    __syncthreads();
    // joint Hillis-Steele: threads 0..511 scan hist, threads 512..767 scan gcount
    for (int o = 1; o < 512; o <<= 1) {
        int add = 0, gadd = 0;
        int tg = t - 512;
        if (t < 512 && t >= o) add = scn[t - o];
        if (tg >= o && tg < 256 && o < 256) gadd = gpre[tg - o];
        __syncthreads();
        if (t < 512) scn[t] += add;
        if (tg >= o && tg < 256 && o < 256) gpre[tg] += gadd;
        __syncthreads();
    }
    int base = gpre[b] - sz;   // exclusive prefix of gcount
    if (t < 512) {
        int excl = scn[t] - v;
        int n = (b << BSH) + t;
        if (n < N_NODES) off[n] = base + excl;
        cur[t] = excl;
    }
    if (b == 0 && t == 0) off[N_NODES] = ET;
    __syncthreads();
    for (int k = t; k < sz; k += 1024) {
        int p = staging[b * BSTRIDE + k];
        int slot = atomicAdd(&cur[p & 511], 1);
        perm[base + slot] = p >> BSH;
    }
}

// ---------------- W swizzle: fp32 row-major -> bf16 MFMA B-fragment order --
// Blocks 0-7: Wp (proj); 8-23: layer0 Wl|Wr; 24-39: layer1 Wl|Wr.

__global__ void swizzle_kernel(const float* __restrict__ Wp,
                               const float* __restrict__ Wl,
                               const float* __restrict__ Wr,
                               ushort* __restrict__ wbp,
                               ushort* __restrict__ wbl0,
                               ushort* __restrict__ wbl1) {
    int bb = blockIdx.x, t = threadIdx.x;
    const float *W0, *W1; ushort* out; int nt;
    if (bb < 8)       { W0 = Wp; W1 = Wp; out = wbp; nt = bb; }
    else if (bb < 24) { W0 = Wl; W1 = Wr; out = wbl0; nt = bb - 8; }
    else              { W0 = Wl + FDIM * FDIM; W1 = Wr + FDIM * FDIM; out = wbl1; nt = bb - 24; }
    int kk = t >> 6, lane = t & 63;
    int n = nt * 16 + (lane & 15);
    int k0 = kk * 32 + (lane >> 4) * 8;
    const float* W = (n < 128) ? (W0 + n) : (W1 + (n - 128));
    float f[8];
#pragma unroll
    for (int j = 0; j < 8; j++) f[j] = W[(size_t)(k0 + j) * FDIM];
    uint4 u;
    u.x = pk_bf16(f[0], f[1]); u.y = pk_bf16(f[2], f[3]);
    u.z = pk_bf16(f[4], f[5]); u.w = pk_bf16(f[6], f[7]);
    *(uint4*)&out[(size_t)((nt * 4 + kk) * 64 + lane) * 8] = u;
}

// ---------------- MFMA GEMM kernels: one wave per 16 rows, no barriers -----

// xl(fp16) = LN(h)@Wl + bl ; xr(fp16) = LN(h)@Wr + br
__global__ __launch_bounds__(256) void ln_gemm2_kernel(
        const float* __restrict__ h,
        const float* __restrict__ g, const float* __restrict__ b,
        const ushort* __restrict__ wb, const float* __restrict__ bl,
        const float* __restrict__ br,
        ushort* __restrict__ xlh, ushort* __restrict__ xrh) {
    __shared__ uint4 fragbuf[4 * 272];
    int wid = (blockIdx.x * 256 + threadIdx.x) >> 6;
    int lane = threadIdx.x & 63;
    if (wid >= N_NODES / 16) return;
    uint4* fb = fragbuf + (threadIdx.x >> 6) * 272;
    int q = lane >> 4, m = lane & 15;
    int row0 = wid * 16;
    const float* hrow = h + (size_t)(row0 + m) * FDIM + q * 32;
    float v[32];
#pragma unroll
    for (int i = 0; i < 8; i++) {
        float4 t4 = *(const float4*)&hrow[i * 4];
        v[i * 4 + 0] = t4.x; v[i * 4 + 1] = t4.y; v[i * 4 + 2] = t4.z; v[i * 4 + 3] = t4.w;
    }
    float s = 0.f, ss = 0.f;
#pragma unroll
    for (int i = 0; i < 32; i++) { s += v[i]; ss += v[i] * v[i]; }
    s  += __shfl_xor(s, 16);  s  += __shfl_xor(s, 32);
    ss += __shfl_xor(ss, 16); ss += __shfl_xor(ss, 32);
    float mu = s * (1.f / 128.f);
    float var = ss * (1.f / 128.f) - mu * mu;
    float rv = rsqrtf(var + EPS);
#pragma unroll
    for (int i = 0; i < 8; i++) {
        float4 gv = *(const float4*)&g[q * 32 + i * 4];
        float4 bv = *(const float4*)&b[q * 32 + i * 4];
        v[i * 4 + 0] = (v[i * 4 + 0] - mu) * rv * gv.x + bv.x;
        v[i * 4 + 1] = (v[i * 4 + 1] - mu) * rv * gv.y + bv.y;
        v[i * 4 + 2] = (v[i * 4 + 2] - mu) * rv * gv.z + bv.z;
        v[i * 4 + 3] = (v[i * 4 + 3] - mu) * rv * gv.w + bv.w;
    }
#pragma unroll
    for (int p = 0; p < 4; p++) {
        uint4 u;
        u.x = pk_bf16(v[p * 8 + 0], v[p * 8 + 1]);
        u.y = pk_bf16(v[p * 8 + 2], v[p * 8 + 3]);
        u.z = pk_bf16(v[p * 8 + 4], v[p * 8 + 5]);
        u.w = pk_bf16(v[p * 8 + 6], v[p * 8 + 7]);
        fb[q * 68 + p * 17 + m] = u;      // [kk=q][p][m]
    }
    bf16x8 A[4];
#pragma unroll
    for (int kk = 0; kk < 4; kk++)
        A[kk] = *(const bf16x8*)&fb[kk * 68 + q * 17 + m];   // [kk][p=q][m]
    const bf16x8* wbv = (const bf16x8*)wb;
    f32x4 acc[16];
    f32x4 z = {0.f, 0.f, 0.f, 0.f};
#pragma unroll
    for (int nt = 0; nt < 16; nt++) acc[nt] = z;
#pragma unroll
    for (int nt = 0; nt < 16; nt++) {
#pragma unroll
        for (int kk = 0; kk < 4; kk++) {
            bf16x8 B = wbv[(nt * 4 + kk) * 64 + lane];
            acc[nt] = __builtin_amdgcn_mfma_f32_16x16x32_bf16(A[kk], B, acc[nt], 0, 0, 0);
        }
    }
#pragma unroll
    for (int nt = 0; nt < 16; nt++) {
        int col = nt * 16 + m;
        if (nt < 8) {
            float bias = bl[col];
#pragma unroll
            for (int r = 0; r < 4; r++) {
                _Float16 hf = (_Float16)(acc[nt][r] + bias);
                xlh[(size_t)(row0 + q * 4 + r) * FDIM + col] = __builtin_bit_cast(ushort, hf);
            }
        } else {
            int c2 = col - 128;
            float bias = br[c2];
#pragma unroll
            for (int r = 0; r < 4; r++) {
                _Float16 hf = (_Float16)(acc[nt][r] + bias);
                xrh[(size_t)(row0 + q * 4 + r) * FDIM + c2] = __builtin_bit_cast(ushort, hf);
            }
        }
    }
}

// h = x @ Wp + bp (fp32 out), same structure, N=128 (8 tiles), no LN
__global__ __launch_bounds__(256) void proj_kernel(
        const float* __restrict__ x, const ushort* __restrict__ wb,
        const float* __restrict__ bp, float* __restrict__ h) {
    __shared__ uint4 fragbuf[4 * 272];
    int wid = (blockIdx.x * 256 + threadIdx.x) >> 6;
    int lane = threadIdx.x & 63;
    if (wid >= N_NODES / 16) return;
    uint4* fb = fragbuf + (threadIdx.x >> 6) * 272;
    int q = lane >> 4, m = lane & 15;
    int row0 = wid * 16;
    const float* xrow = x + (size_t)(row0 + m) * FDIM + q * 32;
#pragma unroll
    for (int p = 0; p < 4; p++) {
        float4 a = *(const float4*)&xrow[p * 8];
        float4 c = *(const float4*)&xrow[p * 8 + 4];
        uint4 u;
        u.x = pk_bf16(a.x, a.y); u.y = pk_bf16(a.z, a.w);
        u.z = pk_bf16(c.x, c.y); u.w = pk_bf16(c.z, c.w);
        fb[q * 68 + p * 17 + m] = u;
    }
    bf16x8 A[4];
#pragma unroll
    for (int kk = 0; kk < 4; kk++)
        A[kk] = *(const bf16x8*)&fb[kk * 68 + q * 17 + m];
    const bf16x8* wbv = (const bf16x8*)wb;
    f32x4 acc[8];
    f32x4 z = {0.f, 0.f, 0.f, 0.f};
#pragma unroll
    for (int nt = 0; nt < 8; nt++) acc[nt] = z;
#pragma unroll
    for (int nt = 0; nt < 8; nt++) {
#pragma unroll
        for (int kk = 0; kk < 4; kk++) {
            bf16x8 B = wbv[(nt * 4 + kk) * 64 + lane];
            acc[nt] = __builtin_amdgcn_mfma_f32_16x16x32_bf16(A[kk], B, acc[nt], 0, 0, 0);
        }
    }
#pragma unroll
    for (int nt = 0; nt < 8; nt++) {
        int col = nt * 16 + m;
        float bias = bp[col];
#pragma unroll
        for (int r = 0; r < 4; r++)
            h[(size_t)(row0 + q * 4 + r) * FDIM + col] = acc[nt][r] + bias;
    }
}

// classification = h @ Wc + bc, [N,128]@[128,16]
__global__ __launch_bounds__(256) void final_kernel(const float* __restrict__ h,
                                                    const float* __restrict__ Wc,
                                                    const float* __restrict__ bc,
                                                    float* __restrict__ out) {
    __shared__ float sh[16][128];
    int row0 = blockIdx.x * 16;
    int t = threadIdx.x;
    for (int i = t; i < 512; i += 256) {
        int r = i >> 5, c4 = (i & 31) * 4;
        *(float4*)&sh[r][c4] = *(const float4*)&h[(size_t)(row0 + r) * FDIM + c4];
    }
    __syncthreads();
    int m = t >> 4, k = t & 15;
    float acc = 0.f;
    for (int c = 0; c < 128; c += 4) {
        const float4 xv = *(const float4*)&sh[m][c];
        acc += xv.x * Wc[(c + 0) * NK + k] + xv.y * Wc[(c + 1) * NK + k]
             + xv.z * Wc[(c + 2) * NK + k] + xv.w * Wc[(c + 3) * NK + k];
    }
    out[(size_t)(row0 + m) * NK + k] = acc + bc[k];
}

// ---------------- GATv2 aggregation: one wave per node ----------------
// lane holds channels (2*lane, 2*lane+1) as ONE packed fp16 pair.
// Depth-2 software pipeline: perm prefetched 2 blocks ahead, xl gathers
// issued 1 block ahead so L2/L3 gather latency hides under the previous
// block's reduce+FMA phase. Butterfly reduce uses DPP (quad_perm xor1/xor2,
// row_ror:8 for xor8) — only xor4 + the 4 weight broadcasts remain on the
// LDS pipe. fp32 accumulate (exp weights can reach ~e^9).

__global__ __launch_bounds__(256) void gat_agg_kernel(
        const unsigned* __restrict__ xlp, const unsigned* __restrict__ xrp,
        const int* __restrict__ off, const int* __restrict__ perm,
        const float* __restrict__ att, const float* __restrict__ gb,
        float* __restrict__ h) {
    int wave = (blockIdx.x * 256 + threadIdx.x) >> 6;
    unsigned lane = threadIdx.x & 63;
    if (wave >= N_NODES) return;
    int i = wave;
    h2 xrv = as_h2(xrp[(unsigned)i * 64u + lane]);
    // hoist epilogue loads so their latency hides under the edge loop
    const float2 hid = *(const float2*)&h[(size_t)i * FDIM + lane * 2];
    const float2 gbv = *(const float2*)&gb[lane * 2];
    float2 attf = *(const float2*)&att[lane * 2];
    h2 attp; attp[0] = (_Float16)attf.x; attp[1] = (_Float16)attf.y;
    const h2 c06 = {(_Float16)0.6f, (_Float16)0.6f};
    const h2 c04 = {(_Float16)0.4f, (_Float16)0.4f};
    bool b0 = lane & 1, b1 = lane & 2;
    int beg = __builtin_amdgcn_readfirstlane(off[i]);
    int end = __builtin_amdgcn_readfirstlane(off[i + 1]);
    float accx = 0.f, accy = 0.f, dloc = 0.f;

    // t = att . leaky(xl_j + xr_i) over this lane's 2 channels
#define EDGE_PARTIAL(U, T)                                          \
    {                                                               \
        h2 mm = as_h2(U) + xrv;                                     \
        h2 am = as_h2(as_u(mm) & 0x7FFF7FFFu);                      \
        h2 sv = am * c04 + mm * c06;                                \
        T = __builtin_amdgcn_fdot2(sv, attp, 0.f, false);           \
    }

    int nb = (end - beg) >> 2;          // full 4-edge blocks
    unsigned cu0, cu1, cu2, cu3;        // gathers in flight for current block
    int nj0, nj1, nj2, nj3;             // perm entries for next block
    if (nb > 0) {
        int q0 = beg;
        int j0 = perm[q0], j1 = perm[q0 + 1], j2 = perm[q0 + 2], j3 = perm[q0 + 3];
        cu0 = xlp[(unsigned)j0 * 64u + lane];
        cu1 = xlp[(unsigned)j1 * 64u + lane];
        cu2 = xlp[(unsigned)j2 * 64u + lane];
        cu3 = xlp[(unsigned)j3 * 64u + lane];
        int q1 = (nb > 1) ? beg + 4 : beg;
        nj0 = perm[q1]; nj1 = perm[q1 + 1]; nj2 = perm[q1 + 2]; nj3 = perm[q1 + 3];
    }
    for (int blk = 0; blk < nb; ++blk) {
        unsigned u0 = cu0, u1 = cu1, u2 = cu2, u3 = cu3;   // vmcnt wait lands here
        if (blk + 1 < nb) {
            // issue next block's gathers (perm already resident in nj*)
            cu0 = xlp[(unsigned)nj0 * 64u + lane];
            cu1 = xlp[(unsigned)nj1 * 64u + lane];
            cu2 = xlp[(unsigned)nj2 * 64u + lane];
            cu3 = xlp[(unsigned)nj3 * 64u + lane];
            int q2 = beg + 4 * ((blk + 2 < nb) ? blk + 2 : blk + 1);
            nj0 = perm[q2]; nj1 = perm[q2 + 1]; nj2 = perm[q2 + 2]; nj3 = perm[q2 + 3];
        }
        float t0, t1, t2, t3;
        EDGE_PARTIAL(u0, t0);
        EDGE_PARTIAL(u1, t1);
        EDGE_PARTIAL(u2, t2);
        EDGE_PARTIAL(u3, t3);
        // simultaneous select+butterfly: lane ends with the full 16-lane sum
        // of edge (lane & 3); xor1/xor2 via DPP quad_perm, xor8 via row_ror:8
        float u   = b0 ? t1 : t0;
        float uu2 = b0 ? t0 : t1;
        u += DX1(uu2);
        float vv  = b0 ? t3 : t2;
        float vv2 = b0 ? t2 : t3;
        vv += DX1(vv2);
        float ww  = b1 ? vv : u;
        float ww2 = b1 ? u : vv;
        ww += DX2(ww2);
        ww += SWZ(ww, 0x101F);      // xor4 (no DPP equivalent)
        ww += DR8(ww);              // xor8
        // softmax shift-invariance: skip segment_max (logits bounded ~|9|)
        float ew = __expf(ww);
        dloc += ew;   // lane's edge only; subgroup-summed in epilogue
        float w0 = SWZ(ew, 0x10);   // broadcast group lane 0
        float w1 = SWZ(ew, 0x30);   // group lane 1
        float w2 = SWZ(ew, 0x50);   // group lane 2
        float w3 = SWZ(ew, 0x70);   // group lane 3
        h2 h0 = as_h2(u0), h1 = as_h2(u1), h22 = as_h2(u2), h3 = as_h2(u3);
        accx = fmaf(w0, (float)h0[0], accx); accy = fmaf(w0, (float)h0[1], accy);
        accx = fmaf(w1, (float)h1[0], accx); accy = fmaf(w1, (float)h1[1], accy);
        accx = fmaf(w2, (float)h22[0], accx); accy = fmaf(w2, (float)h22[1], accy);
        accx = fmaf(w3, (float)h3[0], accx); accy = fmaf(w3, (float)h3[1], accy);
    }
    int p = beg + 4 * nb;
    for (; p < end; ++p) {
        int j = perm[p];
        unsigned u = xlp[(unsigned)j * 64u + lane];
        float tt;
        EDGE_PARTIAL(u, tt);
        tt += DX1(tt);
        tt += DX2(tt);
        tt += SWZ(tt, 0x101F);
        tt += DR8(tt);
        float w = __expf(tt);
        if ((lane & 3) == 0) dloc += w;   // count each tail edge once
        h2 hv = as_h2(u);
        accx = fmaf(w, (float)hv[0], accx); accy = fmaf(w, (float)hv[1], accy);
    }
#undef EDGE_PARTIAL

    // den = sum of dloc over the 4-lane subgroup (each edge counted once)
    float den = dloc + DX1(dloc);
    den += DX2(den);
    float inv = 1.f / den;
    float ox = accx * inv + gbv.x;
    float oy = accy * inv + gbv.y;
    float2 res;
    res.x = fmaxf(ox, 0.f) + hid.x;
    res.y = fmaxf(oy, 0.f) + hid.y;
    *(float2*)&h[(size_t)i * FDIM + lane * 2] = res;
}

// ---------------- launch ----------------

extern "C" void kernel_launch(void* const* d_in, const int* in_sizes, int n_in,
                              void* d_out, int out_size, void* d_ws, size_t ws_size,
                              hipStream_t stream) {
    const float* x    = (const float*)d_in[0];
    const int*   ei   = (const int*)  d_in[1];
    const float* Wp   = (const float*)d_in[2];
    const float* bp   = (const float*)d_in[3];
    const float* ln_g = (const float*)d_in[4];
    const float* ln_b = (const float*)d_in[5];
    const float* Wl   = (const float*)d_in[6];
    const float* bl   = (const float*)d_in[7];
    const float* Wr   = (const float*)d_in[8];
    const float* br   = (const float*)d_in[9];
    const float* att  = (const float*)d_in[10];
    const float* gb   = (const float*)d_in[11];
    const float* Wc   = (const float*)d_in[12];
    const float* bc   = (const float*)d_in[13];

    float* out_cls = (float*)d_out;
    float* h = out_cls + (size_t)N_NODES * NK;   // second output region doubles as h buffer

    char* w = (char*)d_ws;
    int* off    = (int*)w; w += (size_t)(N_NODES + 1) * sizeof(int);
    int* gcount = (int*)w; w += 256 * sizeof(int);
    int* perm   = (int*)w; w += (size_t)ET * sizeof(int);
    uintptr_t a = ((uintptr_t)w + 255) & ~(uintptr_t)255;
    ushort* xlh = (ushort*)a;                             // [N][128] fp16
    ushort* xrh = xlh + (size_t)N_NODES * FDIM;           // [N][128] fp16
    ushort* wbp = xrh + (size_t)N_NODES * FDIM;             // proj W swizzled (32 KB)
    ushort* wbl0 = wbp + 8 * 4 * 64 * 8;                    // layer0 Wl|Wr (64 KB)
    ushort* wbl1 = wbl0 + 16 * 4 * 64 * 8;                  // layer1
    int* staging = (int*)xlh;   // phase-1 staging aliases xlh (8 MB; dead before ln_gemm2)

    // W swizzles (one launch for all three targets)
    swizzle_kernel<<<40, 256, 0, stream>>>(Wp, Wl, Wr, wbp, wbl0, wbl1);

    // CSR by dst (rebuilt every call — ws is re-poisoned)
    hipMemsetAsync(gcount, 0, NBKT * sizeof(int), stream);
    part_kernel<<<(ET + P1_EPB - 1) / P1_EPB, 256, 0, stream>>>(ei, gcount, staging);
    bucket_csr_kernel<<<NBKT, 1024, 0, stream>>>(staging, gcount, off, perm);

    const int gw = (N_NODES / 16 + 3) / 4;   // 1563 blocks (4 waves/block, 16 rows/wave)
    proj_kernel<<<gw, 256, 0, stream>>>(x, wbp, bp, h);

    for (int l = 0; l < 2; ++l) {
        ln_gemm2_kernel<<<gw, 256, 0, stream>>>(
            h, ln_g + l * FDIM, ln_b + l * FDIM,
            (l == 0) ? wbl0 : wbl1, bl + l * FDIM, br + l * FDIM,
            xlh, xrh);
        gat_agg_kernel<<<N_NODES / 4, 256, 0, stream>>>(
            (const unsigned*)xlh, (const unsigned*)xrh, off, perm,
            att + l * FDIM, gb + l * FDIM, h);
    }

    final_kernel<<<N_NODES / 16, 256, 0, stream>>>(h, Wc, bc, out_cls);
}

// Round 4
// 449.533 us; speedup vs baseline: 1.0040x; 1.0040x over previous
//
#include <hip/hip_runtime.h>
#include <hip/hip_bf16.h>
#include <math.h>
#include <stdint.h>

#define N_NODES 100000
#define N_EDGES 1600000
#define ET (N_EDGES + N_NODES)   // 1,700,000 edges incl. self-loops
#define FDIM 128
#define NK 16
#define EPS 1e-5f
#define SLOPE 0.2f

typedef __attribute__((ext_vector_type(8))) short bf16x8;
typedef __attribute__((ext_vector_type(4))) float f32x4;
typedef __attribute__((ext_vector_type(2))) _Float16 h2;

__device__ inline unsigned pk_bf16(float a, float b) {
    float2 f; f.x = a; f.y = b;
    __hip_bfloat162 t = __float22bfloat162_rn(f);
    return *reinterpret_cast<unsigned*>(&t);
}
__device__ inline h2 as_h2(unsigned u) { return __builtin_bit_cast(h2, u); }
__device__ inline unsigned as_u(h2 v) { return __builtin_bit_cast(unsigned, v); }

// single-instruction lane swizzle (BitMode: src = ((lane&and)|or)^xor)
#define SWZ(X, P) __int_as_float(__builtin_amdgcn_ds_swizzle(__float_as_int(X), (P)))
// DPP lane permutes (VALU-pipe, no LDS latency)
#define DPPF(X, CTRL) __int_as_float(__builtin_amdgcn_mov_dpp(__float_as_int(X), (CTRL), 0xF, 0xF, true))
#define DX1(X) DPPF(X, 0xB1)    // quad_perm [1,0,3,2]  == xor 1
#define DX2(X) DPPF(X, 0x4E)    // quad_perm [2,3,0,1]  == xor 2
#define DR8(X) DPPF(X, 0x128)   // row_ror:8            == xor 8 within 16-row

// exp2 on the transcendental pipe (D = 2^S0), guaranteed gfx950 encoding
__device__ inline float exp2_hw(float x) {
    float r;
    asm("v_exp_f32 %0, %1" : "=v"(r) : "v"(x));
    return r;
}

// fused fp16->fp32 multiply-accumulate: ACC += half(U) * W  (1 VALU op,
// replaces v_cvt_f32_f16 + v_fma_f32)
#define FMAMIX_LO(ACC, U, W) \
    asm("v_fma_mix_f32 %0, %1, %2, %0 op_sel_hi:[1,0,0]" : "+v"(ACC) : "v"(U), "v"(W))
#define FMAMIX_HI(ACC, U, W) \
    asm("v_fma_mix_f32 %0, %1, %2, %0 op_sel:[1,0,0] op_sel_hi:[1,0,0]" : "+v"(ACC) : "v"(U), "v"(W))

// ---------------- CSR build: 2-phase bucket partition ----------------

#define NBKT 196
#define BSH 9                      // 512 nodes / bucket
#define BSTRIDE 10240              // staging stride (mean 8704, sigma 93 -> +16 sigma)
#define P1_EPT 8
#define P1_EPB (256 * P1_EPT)      // 2048 edges / block

__global__ __launch_bounds__(256) void part_kernel(const int* __restrict__ ei,
                                                   int* __restrict__ gcount,
                                                   int* __restrict__ staging) {
    __shared__ int hist[NBKT];
    __shared__ int lofs[NBKT];
    __shared__ int gbase[NBKT];
    __shared__ int s[256];
    __shared__ int spk[P1_EPB];
    __shared__ short sbk[P1_EPB];
    int t = threadIdx.x;
    if (t < NBKT) hist[t] = 0;
    __syncthreads();
    int e0 = blockIdx.x * P1_EPB + t;
    int pk[P1_EPT], bk[P1_EPT], rk[P1_EPT];
#pragma unroll
    for (int k = 0; k < P1_EPT; k++) {
        int e = e0 + k * 256;
        bk[k] = -1;
        if (e < ET) {
            int src, dst;
            if (e < N_EDGES) { src = ei[e]; dst = ei[N_EDGES + e]; }
            else             { src = dst = e - N_EDGES; }
            int b = dst >> BSH;
            pk[k] = (src << BSH) | (dst & 511);
            bk[k] = b;
            rk[k] = atomicAdd(&hist[b], 1);
        }
    }
    __syncthreads();
    int v = (t < NBKT) ? hist[t] : 0;
    s[t] = v;
    __syncthreads();
    for (int o = 1; o < 256; o <<= 1) {
        int add = (t >= o) ? s[t - o] : 0;
        __syncthreads();
        s[t] += add;
        __syncthreads();
    }
    if (t < NBKT) {
        lofs[t] = s[t] - v;                    // block-local exclusive offset
        gbase[t] = (v > 0) ? atomicAdd(&gcount[t], v) : 0;
    }
    __syncthreads();
#pragma unroll
    for (int k = 0; k < P1_EPT; k++) {
        if (bk[k] >= 0) {
            int idx = lofs[bk[k]] + rk[k];
            spk[idx] = pk[k];
            sbk[idx] = (short)bk[k];
        }
    }
    __syncthreads();
    int tot = lofs[NBKT - 1] + hist[NBKT - 1];
    for (int i = t; i < tot; i += 256) {
        int b = sbk[i];
        staging[b * BSTRIDE + gbase[b] + (i - lofs[b])] = spk[i];
    }
}

// bucket CSR with fused global bucket-base scan
__global__ __launch_bounds__(1024) void bucket_csr_kernel(
        const int* __restrict__ staging, const int* __restrict__ gcount,
        int* __restrict__ off, int* __restrict__ perm) {
    __shared__ int hist[512];
    __shared__ int scn[512];
    __shared__ int cur[512];
    __shared__ int gpre[256];
    int b = blockIdx.x;
    int t = threadIdx.x;
    if (t < 512) hist[t] = 0;
    if (t < 256) gpre[t] = (t < NBKT) ? gcount[t] : 0;
    __syncthreads();
    int sz = gcount[b];
    for (int k = t; k < sz; k += 1024)
        atomicAdd(&hist[staging[b * BSTRIDE + k] & 511], 1);
    __syncthreads();
    int v = (t < 512) ? hist[t] : 0;
    if (t < 512) scn[t] = v;
    __syncthreads();
    // joint Hillis-Steele: threads 0..511 scan hist, threads 512..767 scan gcount
    for (int o = 1; o < 512; o <<= 1) {
        int add = 0, gadd = 0;
        int tg = t - 512;
        if (t < 512 && t >= o) add = scn[t - o];
        if (tg >= o && tg < 256 && o < 256) gadd = gpre[tg - o];
        __syncthreads();
        if (t < 512) scn[t] += add;
        if (tg >= o && tg < 256 && o < 256) gpre[tg] += gadd;
        __syncthreads();
    }
    int base = gpre[b] - sz;   // exclusive prefix of gcount
    if (t < 512) {
        int excl = scn[t] - v;
        int n = (b << BSH) + t;
        if (n < N_NODES) off[n] = base + excl;
        cur[t] = excl;
    }
    if (b == 0 && t == 0) off[N_NODES] = ET;
    __syncthreads();
    for (int k = t; k < sz; k += 1024) {
        int p = staging[b * BSTRIDE + k];
        int slot = atomicAdd(&cur[p & 511], 1);
        perm[base + slot] = p >> BSH;
    }
}

// ---------------- W swizzle: fp32 row-major -> bf16 MFMA B-fragment order --
// Blocks 0-7: Wp (proj); 8-23: layer0 Wl|Wr; 24-39: layer1 Wl|Wr.

__global__ void swizzle_kernel(const float* __restrict__ Wp,
                               const float* __restrict__ Wl,
                               const float* __restrict__ Wr,
                               ushort* __restrict__ wbp,
                               ushort* __restrict__ wbl0,
                               ushort* __restrict__ wbl1) {
    int bb = blockIdx.x, t = threadIdx.x;
    const float *W0, *W1; ushort* out; int nt;
    if (bb < 8)       { W0 = Wp; W1 = Wp; out = wbp; nt = bb; }
    else if (bb < 24) { W0 = Wl; W1 = Wr; out = wbl0; nt = bb - 8; }
    else              { W0 = Wl + FDIM * FDIM; W1 = Wr + FDIM * FDIM; out = wbl1; nt = bb - 24; }
    int kk = t >> 6, lane = t & 63;
    int n = nt * 16 + (lane & 15);
    int k0 = kk * 32 + (lane >> 4) * 8;
    const float* W = (n < 128) ? (W0 + n) : (W1 + (n - 128));
    float f[8];
#pragma unroll
    for (int j = 0; j < 8; j++) f[j] = W[(size_t)(k0 + j) * FDIM];
    uint4 u;
    u.x = pk_bf16(f[0], f[1]); u.y = pk_bf16(f[2], f[3]);
    u.z = pk_bf16(f[4], f[5]); u.w = pk_bf16(f[6], f[7]);
    *(uint4*)&out[(size_t)((nt * 4 + kk) * 64 + lane) * 8] = u;
}

// ---------------- MFMA GEMM kernels: one wave per 16 rows, no barriers -----

// xl(fp16) = LN(h)@Wl + bl ; xr(fp16) = LN(h)@Wr + br
__global__ __launch_bounds__(256) void ln_gemm2_kernel(
        const float* __restrict__ h,
        const float* __restrict__ g, const float* __restrict__ b,
        const ushort* __restrict__ wb, const float* __restrict__ bl,
        const float* __restrict__ br,
        ushort* __restrict__ xlh, ushort* __restrict__ xrh) {
    __shared__ uint4 fragbuf[4 * 272];
    int wid = (blockIdx.x * 256 + threadIdx.x) >> 6;
    int lane = threadIdx.x & 63;
    if (wid >= N_NODES / 16) return;
    uint4* fb = fragbuf + (threadIdx.x >> 6) * 272;
    int q = lane >> 4, m = lane & 15;
    int row0 = wid * 16;
    const float* hrow = h + (size_t)(row0 + m) * FDIM + q * 32;
    float v[32];
#pragma unroll
    for (int i = 0; i < 8; i++) {
        float4 t4 = *(const float4*)&hrow[i * 4];
        v[i * 4 + 0] = t4.x; v[i * 4 + 1] = t4.y; v[i * 4 + 2] = t4.z; v[i * 4 + 3] = t4.w;
    }
    float s = 0.f, ss = 0.f;
#pragma unroll
    for (int i = 0; i < 32; i++) { s += v[i]; ss += v[i] * v[i]; }
    s  += __shfl_xor(s, 16);  s  += __shfl_xor(s, 32);
    ss += __shfl_xor(ss, 16); ss += __shfl_xor(ss, 32);
    float mu = s * (1.f / 128.f);
    float var = ss * (1.f / 128.f) - mu * mu;
    float rv = rsqrtf(var + EPS);
#pragma unroll
    for (int i = 0; i < 8; i++) {
        float4 gv = *(const float4*)&g[q * 32 + i * 4];
        float4 bv = *(const float4*)&b[q * 32 + i * 4];
        v[i * 4 + 0] = (v[i * 4 + 0] - mu) * rv * gv.x + bv.x;
        v[i * 4 + 1] = (v[i * 4 + 1] - mu) * rv * gv.y + bv.y;
        v[i * 4 + 2] = (v[i * 4 + 2] - mu) * rv * gv.z + bv.z;
        v[i * 4 + 3] = (v[i * 4 + 3] - mu) * rv * gv.w + bv.w;
    }
#pragma unroll
    for (int p = 0; p < 4; p++) {
        uint4 u;
        u.x = pk_bf16(v[p * 8 + 0], v[p * 8 + 1]);
        u.y = pk_bf16(v[p * 8 + 2], v[p * 8 + 3]);
        u.z = pk_bf16(v[p * 8 + 4], v[p * 8 + 5]);
        u.w = pk_bf16(v[p * 8 + 6], v[p * 8 + 7]);
        fb[q * 68 + p * 17 + m] = u;      // [kk=q][p][m]
    }
    bf16x8 A[4];
#pragma unroll
    for (int kk = 0; kk < 4; kk++)
        A[kk] = *(const bf16x8*)&fb[kk * 68 + q * 17 + m];   // [kk][p=q][m]
    const bf16x8* wbv = (const bf16x8*)wb;
    f32x4 acc[16];
    f32x4 z = {0.f, 0.f, 0.f, 0.f};
#pragma unroll
    for (int nt = 0; nt < 16; nt++) acc[nt] = z;
#pragma unroll
    for (int nt = 0; nt < 16; nt++) {
#pragma unroll
        for (int kk = 0; kk < 4; kk++) {
            bf16x8 B = wbv[(nt * 4 + kk) * 64 + lane];
            acc[nt] = __builtin_amdgcn_mfma_f32_16x16x32_bf16(A[kk], B, acc[nt], 0, 0, 0);
        }
    }
#pragma unroll
    for (int nt = 0; nt < 16; nt++) {
        int col = nt * 16 + m;
        if (nt < 8) {
            float bias = bl[col];
#pragma unroll
            for (int r = 0; r < 4; r++) {
                _Float16 hf = (_Float16)(acc[nt][r] + bias);
                xlh[(size_t)(row0 + q * 4 + r) * FDIM + col] = __builtin_bit_cast(ushort, hf);
            }
        } else {
            int c2 = col - 128;
            float bias = br[c2];
#pragma unroll
            for (int r = 0; r < 4; r++) {
                _Float16 hf = (_Float16)(acc[nt][r] + bias);
                xrh[(size_t)(row0 + q * 4 + r) * FDIM + c2] = __builtin_bit_cast(ushort, hf);
            }
        }
    }
}

// h = x @ Wp + bp (fp32 out), same structure, N=128 (8 tiles), no LN
__global__ __launch_bounds__(256) void proj_kernel(
        const float* __restrict__ x, const ushort* __restrict__ wb,
        const float* __restrict__ bp, float* __restrict__ h) {
    __shared__ uint4 fragbuf[4 * 272];
    int wid = (blockIdx.x * 256 + threadIdx.x) >> 6;
    int lane = threadIdx.x & 63;
    if (wid >= N_NODES / 16) return;
    uint4* fb = fragbuf + (threadIdx.x >> 6) * 272;
    int q = lane >> 4, m = lane & 15;
    int row0 = wid * 16;
    const float* xrow = x + (size_t)(row0 + m) * FDIM + q * 32;
#pragma unroll
    for (int p = 0; p < 4; p++) {
        float4 a = *(const float4*)&xrow[p * 8];
        float4 c = *(const float4*)&xrow[p * 8 + 4];
        uint4 u;
        u.x = pk_bf16(a.x, a.y); u.y = pk_bf16(a.z, a.w);
        u.z = pk_bf16(c.x, c.y); u.w = pk_bf16(c.z, c.w);
        fb[q * 68 + p * 17 + m] = u;
    }
    bf16x8 A[4];
#pragma unroll
    for (int kk = 0; kk < 4; kk++)
        A[kk] = *(const bf16x8*)&fb[kk * 68 + q * 17 + m];
    const bf16x8* wbv = (const bf16x8*)wb;
    f32x4 acc[8];
    f32x4 z = {0.f, 0.f, 0.f, 0.f};
#pragma unroll
    for (int nt = 0; nt < 8; nt++) acc[nt] = z;
#pragma unroll
    for (int nt = 0; nt < 8; nt++) {
#pragma unroll
        for (int kk = 0; kk < 4; kk++) {
            bf16x8 B = wbv[(nt * 4 + kk) * 64 + lane];
            acc[nt] = __builtin_amdgcn_mfma_f32_16x16x32_bf16(A[kk], B, acc[nt], 0, 0, 0);
        }
    }
#pragma unroll
    for (int nt = 0; nt < 8; nt++) {
        int col = nt * 16 + m;
        float bias = bp[col];
#pragma unroll
        for (int r = 0; r < 4; r++)
            h[(size_t)(row0 + q * 4 + r) * FDIM + col] = acc[nt][r] + bias;
    }
}

// classification = h @ Wc + bc, [N,128]@[128,16]
__global__ __launch_bounds__(256) void final_kernel(const float* __restrict__ h,
                                                    const float* __restrict__ Wc,
                                                    const float* __restrict__ bc,
                                                    float* __restrict__ out) {
    __shared__ float sh[16][128];
    int row0 = blockIdx.x * 16;
    int t = threadIdx.x;
    for (int i = t; i < 512; i += 256) {
        int r = i >> 5, c4 = (i & 31) * 4;
        *(float4*)&sh[r][c4] = *(const float4*)&h[(size_t)(row0 + r) * FDIM + c4];
    }
    __syncthreads();
    int m = t >> 4, k = t & 15;
    float acc = 0.f;
    for (int c = 0; c < 128; c += 4) {
        const float4 xv = *(const float4*)&sh[m][c];
        acc += xv.x * Wc[(c + 0) * NK + k] + xv.y * Wc[(c + 1) * NK + k]
             + xv.z * Wc[(c + 2) * NK + k] + xv.w * Wc[(c + 3) * NK + k];
    }
    out[(size_t)(row0 + m) * NK + k] = acc + bc[k];
}

// ---------------- GATv2 aggregation: one wave per node ----------------
// lane holds channels (2*lane, 2*lane+1) as ONE packed fp16 pair.
// VALU-lean inner loop: scalar (readfirstlane) perm indices -> saddr+voffset
// gathers (1 VALU/gather); att pre-scaled by log2(e) so the softmax weight is
// a bare v_exp_f32; accumulation via v_fma_mix_f32 (packed fp16 source, fp32
// accum, no separate cvt). Depth-2 pipeline: block n+1's gathers issue before
// block n's compute; #pragma unroll 2 renames the register rotation away.

__global__ __launch_bounds__(256) void gat_agg_kernel(
        const unsigned* __restrict__ xlp, const unsigned* __restrict__ xrp,
        const int* __restrict__ off, const int* __restrict__ perm,
        const float* __restrict__ att, const float* __restrict__ gb,
        float* __restrict__ h) {
    int wave = (blockIdx.x * 256 + threadIdx.x) >> 6;
    unsigned lane = threadIdx.x & 63;
    if (wave >= N_NODES) return;
    int i = wave;
    h2 xrv = as_h2(xrp[(unsigned)i * 64u + lane]);
    // hoist epilogue loads so their latency hides under the edge loop
    const float2 hid = *(const float2*)&h[(size_t)i * FDIM + lane * 2];
    const float2 gbv = *(const float2*)&gb[lane * 2];
    float2 attf = *(const float2*)&att[lane * 2];
    // fold ln2 rebase into att: exp(att.s) == exp2((att*log2e).s)
    h2 attp; attp[0] = (_Float16)(attf.x * 1.44269504f);
    attp[1] = (_Float16)(attf.y * 1.44269504f);
    const h2 c06 = {(_Float16)0.6f, (_Float16)0.6f};
    const h2 c04 = {(_Float16)0.4f, (_Float16)0.4f};
    bool b0 = lane & 1, b1 = lane & 2;
    int beg = __builtin_amdgcn_readfirstlane(off[i]);
    int end = __builtin_amdgcn_readfirstlane(off[i + 1]);
    float accx = 0.f, accy = 0.f, dloc = 0.f;
    const char* xlB = (const char*)xlp;
    unsigned laneB = lane << 2;

    // t = att . leaky(xl_j + xr_i) over this lane's 2 channels (log2 domain)
#define EDGE_PARTIAL(U, T)                                          \
    {                                                               \
        h2 mm = as_h2(U) + xrv;                                     \
        h2 am = as_h2(as_u(mm) & 0x7FFF7FFFu);                      \
        h2 sv = am * c04 + mm * c06;                                \
        T = __builtin_amdgcn_fdot2(sv, attp, 0.f, false);           \
    }

    // full 4-edge block: partials, select+butterfly (DPP), exp2, 4 weight
    // broadcasts, 8 fma_mix accumulates
#define COMPUTE4(U0, U1, U2, U3)                                    \
    {                                                               \
        float t0, t1, t2, t3;                                       \
        EDGE_PARTIAL(U0, t0);                                       \
        EDGE_PARTIAL(U1, t1);                                       \
        EDGE_PARTIAL(U2, t2);                                       \
        EDGE_PARTIAL(U3, t3);                                       \
        float u   = b0 ? t1 : t0;                                   \
        float uu2 = b0 ? t0 : t1;                                   \
        u += DX1(uu2);                                              \
        float vv  = b0 ? t3 : t2;                                   \
        float vv2 = b0 ? t2 : t3;                                   \
        vv += DX1(vv2);                                             \
        float ww  = b1 ? vv : u;                                    \
        float ww2 = b1 ? u : vv;                                    \
        ww += DX2(ww2);                                             \
        ww += SWZ(ww, 0x101F);                                      \
        ww += DR8(ww);                                              \
        float ew = exp2_hw(ww);                                     \
        dloc += ew;                                                 \
        float w0 = SWZ(ew, 0x10);                                   \
        float w1 = SWZ(ew, 0x30);                                   \
        float w2 = SWZ(ew, 0x50);                                   \
        float w3 = SWZ(ew, 0x70);                                   \
        FMAMIX_LO(accx, U0, w0); FMAMIX_HI(accy, U0, w0);           \
        FMAMIX_LO(accx, U1, w1); FMAMIX_HI(accy, U1, w1);           \
        FMAMIX_LO(accx, U2, w2); FMAMIX_HI(accy, U2, w2);           \
        FMAMIX_LO(accx, U3, w3); FMAMIX_HI(accy, U3, w3);           \
    }

    int nb = (end - beg) >> 2;          // full 4-edge blocks
    unsigned cu0, cu1, cu2, cu3;        // gathers in flight for current block
    if (nb > 0) {
        int j0 = __builtin_amdgcn_readfirstlane(perm[beg + 0]);
        int j1 = __builtin_amdgcn_readfirstlane(perm[beg + 1]);
        int j2 = __builtin_amdgcn_readfirstlane(perm[beg + 2]);
        int j3 = __builtin_amdgcn_readfirstlane(perm[beg + 3]);
        cu0 = *(const unsigned*)(xlB + ((unsigned)j0 * 256u + laneB));
        cu1 = *(const unsigned*)(xlB + ((unsigned)j1 * 256u + laneB));
        cu2 = *(const unsigned*)(xlB + ((unsigned)j2 * 256u + laneB));
        cu3 = *(const unsigned*)(xlB + ((unsigned)j3 * 256u + laneB));
    }
#pragma unroll 2
    for (int blk = 0; blk + 1 < nb; ++blk) {
        // issue next block's gathers before waiting on the current block
        int q = beg + 4 * blk + 4;
        int j0 = __builtin_amdgcn_readfirstlane(perm[q + 0]);
        int j1 = __builtin_amdgcn_readfirstlane(perm[q + 1]);
        int j2 = __builtin_amdgcn_readfirstlane(perm[q + 2]);
        int j3 = __builtin_amdgcn_readfirstlane(perm[q + 3]);
        unsigned du0 = *(const unsigned*)(xlB + ((unsigned)j0 * 256u + laneB));
        unsigned du1 = *(const unsigned*)(xlB + ((unsigned)j1 * 256u + laneB));
        unsigned du2 = *(const unsigned*)(xlB + ((unsigned)j2 * 256u + laneB));
        unsigned du3 = *(const unsigned*)(xlB + ((unsigned)j3 * 256u + laneB));
        COMPUTE4(cu0, cu1, cu2, cu3);
        cu0 = du0; cu1 = du1; cu2 = du2; cu3 = du3;
    }
    if (nb > 0) COMPUTE4(cu0, cu1, cu2, cu3);

    int p = beg + 4 * nb;
    for (; p < end; ++p) {
        int j = __builtin_amdgcn_readfirstlane(perm[p]);
        unsigned u = *(const unsigned*)(xlB + ((unsigned)j * 256u + laneB));
        float tt;
        EDGE_PARTIAL(u, tt);
        tt += DX1(tt);
        tt += DX2(tt);
        tt += SWZ(tt, 0x101F);
        tt += DR8(tt);
        float w = exp2_hw(tt);
        if ((lane & 3) == 0) dloc += w;   // count each tail edge once
        FMAMIX_LO(accx, u, w); FMAMIX_HI(accy, u, w);
    }
#undef EDGE_PARTIAL
#undef COMPUTE4

    // den = sum of dloc over the 4-lane subgroup (each edge counted once)
    float den = dloc + DX1(dloc);
    den += DX2(den);
    float inv = 1.f / den;
    float ox = accx * inv + gbv.x;
    float oy = accy * inv + gbv.y;
    float2 res;
    res.x = fmaxf(ox, 0.f) + hid.x;
    res.y = fmaxf(oy, 0.f) + hid.y;
    *(float2*)&h[(size_t)i * FDIM + lane * 2] = res;
}

// ---------------- launch ----------------

extern "C" void kernel_launch(void* const* d_in, const int* in_sizes, int n_in,
                              void* d_out, int out_size, void* d_ws, size_t ws_size,
                              hipStream_t stream) {
    const float* x    = (const float*)d_in[0];
    const int*   ei   = (const int*)  d_in[1];
    const float* Wp   = (const float*)d_in[2];
    const float* bp   = (const float*)d_in[3];
    const float* ln_g = (const float*)d_in[4];
    const float* ln_b = (const float*)d_in[5];
    const float* Wl   = (const float*)d_in[6];
    const float* bl   = (const float*)d_in[7];
    const float* Wr   = (const float*)d_in[8];
    const float* br   = (const float*)d_in[9];
    const float* att  = (const float*)d_in[10];
    const float* gb   = (const float*)d_in[11];
    const float* Wc   = (const float*)d_in[12];
    const float* bc   = (const float*)d_in[13];

    float* out_cls = (float*)d_out;
    float* h = out_cls + (size_t)N_NODES * NK;   // second output region doubles as h buffer

    char* w = (char*)d_ws;
    int* off    = (int*)w; w += (size_t)(N_NODES + 1) * sizeof(int);
    int* gcount = (int*)w; w += 256 * sizeof(int);
    int* perm   = (int*)w; w += (size_t)ET * sizeof(int);
    uintptr_t a = ((uintptr_t)w + 255) & ~(uintptr_t)255;
    ushort* xlh = (ushort*)a;                             // [N][128] fp16
    ushort* xrh = xlh + (size_t)N_NODES * FDIM;           // [N][128] fp16
    ushort* wbp = xrh + (size_t)N_NODES * FDIM;             // proj W swizzled (32 KB)
    ushort* wbl0 = wbp + 8 * 4 * 64 * 8;                    // layer0 Wl|Wr (64 KB)
    ushort* wbl1 = wbl0 + 16 * 4 * 64 * 8;                  // layer1
    int* staging = (int*)xlh;   // phase-1 staging aliases xlh (8 MB; dead before ln_gemm2)

    // W swizzles (one launch for all three targets)
    swizzle_kernel<<<40, 256, 0, stream>>>(Wp, Wl, Wr, wbp, wbl0, wbl1);

    // CSR by dst (rebuilt every call — ws is re-poisoned)
    hipMemsetAsync(gcount, 0, NBKT * sizeof(int), stream);
    part_kernel<<<(ET + P1_EPB - 1) / P1_EPB, 256, 0, stream>>>(ei, gcount, staging);
    bucket_csr_kernel<<<NBKT, 1024, 0, stream>>>(staging, gcount, off, perm);

    const int gw = (N_NODES / 16 + 3) / 4;   // 1563 blocks (4 waves/block, 16 rows/wave)
    proj_kernel<<<gw, 256, 0, stream>>>(x, wbp, bp, h);

    for (int l = 0; l < 2; ++l) {
        ln_gemm2_kernel<<<gw, 256, 0, stream>>>(
            h, ln_g + l * FDIM, ln_b + l * FDIM,
            (l == 0) ? wbl0 : wbl1, bl + l * FDIM, br + l * FDIM,
            xlh, xrh);
        gat_agg_kernel<<<N_NODES / 4, 256, 0, stream>>>(
            (const unsigned*)xlh, (const unsigned*)xrh, off, perm,
            att + l * FDIM, gb + l * FDIM, h);
    }

    final_kernel<<<N_NODES / 16, 256, 0, stream>>>(h, Wc, bc, out_cls);
}

// Round 5
// 449.225 us; speedup vs baseline: 1.0047x; 1.0007x over previous
//
#include <hip/hip_runtime.h>
#include <hip/hip_bf16.h>
#include <math.h>
#include <stdint.h>

#define N_NODES 100000
#define N_EDGES 1600000
#define ET (N_EDGES + N_NODES)   // 1,700,000 edges incl. self-loops
#define FDIM 128
#define NK 16
#define EPS 1e-5f
#define SLOPE 0.2f

typedef __attribute__((ext_vector_type(8))) short bf16x8;
typedef __attribute__((ext_vector_type(4))) float f32x4;
typedef __attribute__((ext_vector_type(2))) _Float16 h2;

__device__ inline unsigned pk_bf16(float a, float b) {
    float2 f; f.x = a; f.y = b;
    __hip_bfloat162 t = __float22bfloat162_rn(f);
    return *reinterpret_cast<unsigned*>(&t);
}
__device__ inline h2 as_h2(unsigned u) { return __builtin_bit_cast(h2, u); }
__device__ inline unsigned as_u(h2 v) { return __builtin_bit_cast(unsigned, v); }

// single-instruction lane swizzle (BitMode: src = ((lane&and)|or)^xor)
#define SWZ(X, P) __int_as_float(__builtin_amdgcn_ds_swizzle(__float_as_int(X), (P)))
// DPP lane permutes (VALU-pipe, no LDS latency)
#define DPPF(X, CTRL) __int_as_float(__builtin_amdgcn_mov_dpp(__float_as_int(X), (CTRL), 0xF, 0xF, true))
#define DX1(X) DPPF(X, 0xB1)    // quad_perm [1,0,3,2]  == xor 1
#define DX2(X) DPPF(X, 0x4E)    // quad_perm [2,3,0,1]  == xor 2
#define DR4(X) DPPF(X, 0x124)   // row_ror:4 (quad-id preserving rotate)
#define DR8(X) DPPF(X, 0x128)   // row_ror:8
// quad-level broadcasts: within a quad, lane k holds edge-k's weight
#define DB0(X) DPPF(X, 0x00)    // quad_perm [0,0,0,0]
#define DB1(X) DPPF(X, 0x55)    // quad_perm [1,1,1,1]
#define DB2(X) DPPF(X, 0xAA)    // quad_perm [2,2,2,2]
#define DB3(X) DPPF(X, 0xFF)    // quad_perm [3,3,3,3]

// exp2 on the transcendental pipe (D = 2^S0), guaranteed gfx950 encoding
__device__ inline float exp2_hw(float x) {
    float r;
    asm("v_exp_f32 %0, %1" : "=v"(r) : "v"(x));
    return r;
}

// fused fp16->fp32 multiply-accumulate: ACC += half(U) * W  (1 VALU op)
#define FMAMIX_LO(ACC, U, W) \
    asm("v_fma_mix_f32 %0, %1, %2, %0 op_sel_hi:[1,0,0]" : "+v"(ACC) : "v"(U), "v"(W))
#define FMAMIX_HI(ACC, U, W) \
    asm("v_fma_mix_f32 %0, %1, %2, %0 op_sel:[1,0,0] op_sel_hi:[1,0,0]" : "+v"(ACC) : "v"(U), "v"(W))

// readfirstlane + mask to <2^17: speculative (prefetched) perm entries may be
// garbage; masking keeps the gather offset inside the workspace (<34 MB).
__device__ inline int rflm(int v) { return __builtin_amdgcn_readfirstlane(v) & 131071; }

// ---------------- CSR build: 2-phase bucket partition ----------------

#define NBKT 196
#define BSH 9                      // 512 nodes / bucket
#define BSTRIDE 10240              // staging stride (mean 8704, sigma 93 -> +16 sigma)
#define P1_EPT 8
#define P1_EPB (256 * P1_EPT)      // 2048 edges / block

__global__ __launch_bounds__(256) void part_kernel(const int* __restrict__ ei,
                                                   int* __restrict__ gcount,
                                                   int* __restrict__ staging) {
    __shared__ int hist[NBKT];
    __shared__ int lofs[NBKT];
    __shared__ int gbase[NBKT];
    __shared__ int s[256];
    __shared__ int spk[P1_EPB];
    __shared__ short sbk[P1_EPB];
    int t = threadIdx.x;
    if (t < NBKT) hist[t] = 0;
    __syncthreads();
    int e0 = blockIdx.x * P1_EPB + t;
    int pk[P1_EPT], bk[P1_EPT], rk[P1_EPT];
#pragma unroll
    for (int k = 0; k < P1_EPT; k++) {
        int e = e0 + k * 256;
        bk[k] = -1;
        if (e < ET) {
            int src, dst;
            if (e < N_EDGES) { src = ei[e]; dst = ei[N_EDGES + e]; }
            else             { src = dst = e - N_EDGES; }
            int b = dst >> BSH;
            pk[k] = (src << BSH) | (dst & 511);
            bk[k] = b;
            rk[k] = atomicAdd(&hist[b], 1);
        }
    }
    __syncthreads();
    int v = (t < NBKT) ? hist[t] : 0;
    s[t] = v;
    __syncthreads();
    for (int o = 1; o < 256; o <<= 1) {
        int add = (t >= o) ? s[t - o] : 0;
        __syncthreads();
        s[t] += add;
        __syncthreads();
    }
    if (t < NBKT) {
        lofs[t] = s[t] - v;                    // block-local exclusive offset
        gbase[t] = (v > 0) ? atomicAdd(&gcount[t], v) : 0;
    }
    __syncthreads();
#pragma unroll
    for (int k = 0; k < P1_EPT; k++) {
        if (bk[k] >= 0) {
            int idx = lofs[bk[k]] + rk[k];
            spk[idx] = pk[k];
            sbk[idx] = (short)bk[k];
        }
    }
    __syncthreads();
    int tot = lofs[NBKT - 1] + hist[NBKT - 1];
    for (int i = t; i < tot; i += 256) {
        int b = sbk[i];
        staging[b * BSTRIDE + gbase[b] + (i - lofs[b])] = spk[i];
    }
}

// bucket CSR with fused global bucket-base scan
__global__ __launch_bounds__(1024) void bucket_csr_kernel(
        const int* __restrict__ staging, const int* __restrict__ gcount,
        int* __restrict__ off, int* __restrict__ perm) {
    __shared__ int hist[512];
    __shared__ int scn[512];
    __shared__ int cur[512];
    __shared__ int gpre[256];
    int b = blockIdx.x;
    int t = threadIdx.x;
    if (t < 512) hist[t] = 0;
    if (t < 256) gpre[t] = (t < NBKT) ? gcount[t] : 0;
    __syncthreads();
    int sz = gcount[b];
    for (int k = t; k < sz; k += 1024)
        atomicAdd(&hist[staging[b * BSTRIDE + k] & 511], 1);
    __syncthreads();
    int v = (t < 512) ? hist[t] : 0;
    if (t < 512) scn[t] = v;
    __syncthreads();
    // joint Hillis-Steele: threads 0..511 scan hist, threads 512..767 scan gcount
    for (int o = 1; o < 512; o <<= 1) {
        int add = 0, gadd = 0;
        int tg = t - 512;
        if (t < 512 && t >= o) add = scn[t - o];
        if (tg >= o && tg < 256 && o < 256) gadd = gpre[tg - o];
        __syncthreads();
        if (t < 512) scn[t] += add;
        if (tg >= o && tg < 256 && o < 256) gpre[tg] += gadd;
        __syncthreads();
    }
    int base = gpre[b] - sz;   // exclusive prefix of gcount
    if (t < 512) {
        int excl = scn[t] - v;
        int n = (b << BSH) + t;
        if (n < N_NODES) off[n] = base + excl;
        cur[t] = excl;
    }
    if (b == 0 && t == 0) off[N_NODES] = ET;
    __syncthreads();
    for (int k = t; k < sz; k += 1024) {
        int p = staging[b * BSTRIDE + k];
        int slot = atomicAdd(&cur[p & 511], 1);
        perm[base + slot] = p >> BSH;
    }
}

// ---------------- W swizzle: fp32 row-major -> bf16 MFMA B-fragment order --
// Blocks 0-7: Wp (proj); 8-23: layer0 Wl|Wr; 24-39: layer1 Wl|Wr.

__global__ void swizzle_kernel(const float* __restrict__ Wp,
                               const float* __restrict__ Wl,
                               const float* __restrict__ Wr,
                               ushort* __restrict__ wbp,
                               ushort* __restrict__ wbl0,
                               ushort* __restrict__ wbl1) {
    int bb = blockIdx.x, t = threadIdx.x;
    const float *W0, *W1; ushort* out; int nt;
    if (bb < 8)       { W0 = Wp; W1 = Wp; out = wbp; nt = bb; }
    else if (bb < 24) { W0 = Wl; W1 = Wr; out = wbl0; nt = bb - 8; }
    else              { W0 = Wl + FDIM * FDIM; W1 = Wr + FDIM * FDIM; out = wbl1; nt = bb - 24; }
    int kk = t >> 6, lane = t & 63;
    int n = nt * 16 + (lane & 15);
    int k0 = kk * 32 + (lane >> 4) * 8;
    const float* W = (n < 128) ? (W0 + n) : (W1 + (n - 128));
    float f[8];
#pragma unroll
    for (int j = 0; j < 8; j++) f[j] = W[(size_t)(k0 + j) * FDIM];
    uint4 u;
    u.x = pk_bf16(f[0], f[1]); u.y = pk_bf16(f[2], f[3]);
    u.z = pk_bf16(f[4], f[5]); u.w = pk_bf16(f[6], f[7]);
    *(uint4*)&out[(size_t)((nt * 4 + kk) * 64 + lane) * 8] = u;
}

// ---------------- MFMA GEMM kernels: one wave per 16 rows, no barriers -----

// xl(fp16) = LN(h)@Wl + bl ; xr(fp16) = LN(h)@Wr + br
__global__ __launch_bounds__(256) void ln_gemm2_kernel(
        const float* __restrict__ h,
        const float* __restrict__ g, const float* __restrict__ b,
        const ushort* __restrict__ wb, const float* __restrict__ bl,
        const float* __restrict__ br,
        ushort* __restrict__ xlh, ushort* __restrict__ xrh) {
    __shared__ uint4 fragbuf[4 * 272];
    int wid = (blockIdx.x * 256 + threadIdx.x) >> 6;
    int lane = threadIdx.x & 63;
    if (wid >= N_NODES / 16) return;
    uint4* fb = fragbuf + (threadIdx.x >> 6) * 272;
    int q = lane >> 4, m = lane & 15;
    int row0 = wid * 16;
    const float* hrow = h + (size_t)(row0 + m) * FDIM + q * 32;
    float v[32];
#pragma unroll
    for (int i = 0; i < 8; i++) {
        float4 t4 = *(const float4*)&hrow[i * 4];
        v[i * 4 + 0] = t4.x; v[i * 4 + 1] = t4.y; v[i * 4 + 2] = t4.z; v[i * 4 + 3] = t4.w;
    }
    float s = 0.f, ss = 0.f;
#pragma unroll
    for (int i = 0; i < 32; i++) { s += v[i]; ss += v[i] * v[i]; }
    s  += __shfl_xor(s, 16);  s  += __shfl_xor(s, 32);
    ss += __shfl_xor(ss, 16); ss += __shfl_xor(ss, 32);
    float mu = s * (1.f / 128.f);
    float var = ss * (1.f / 128.f) - mu * mu;
    float rv = rsqrtf(var + EPS);
#pragma unroll
    for (int i = 0; i < 8; i++) {
        float4 gv = *(const float4*)&g[q * 32 + i * 4];
        float4 bv = *(const float4*)&b[q * 32 + i * 4];
        v[i * 4 + 0] = (v[i * 4 + 0] - mu) * rv * gv.x + bv.x;
        v[i * 4 + 1] = (v[i * 4 + 1] - mu) * rv * gv.y + bv.y;
        v[i * 4 + 2] = (v[i * 4 + 2] - mu) * rv * gv.z + bv.z;
        v[i * 4 + 3] = (v[i * 4 + 3] - mu) * rv * gv.w + bv.w;
    }
#pragma unroll
    for (int p = 0; p < 4; p++) {
        uint4 u;
        u.x = pk_bf16(v[p * 8 + 0], v[p * 8 + 1]);
        u.y = pk_bf16(v[p * 8 + 2], v[p * 8 + 3]);
        u.z = pk_bf16(v[p * 8 + 4], v[p * 8 + 5]);
        u.w = pk_bf16(v[p * 8 + 6], v[p * 8 + 7]);
        fb[q * 68 + p * 17 + m] = u;      // [kk=q][p][m]
    }
    bf16x8 A[4];
#pragma unroll
    for (int kk = 0; kk < 4; kk++)
        A[kk] = *(const bf16x8*)&fb[kk * 68 + q * 17 + m];   // [kk][p=q][m]
    const bf16x8* wbv = (const bf16x8*)wb;
    f32x4 acc[16];
    f32x4 z = {0.f, 0.f, 0.f, 0.f};
#pragma unroll
    for (int nt = 0; nt < 16; nt++) acc[nt] = z;
#pragma unroll
    for (int nt = 0; nt < 16; nt++) {
#pragma unroll
        for (int kk = 0; kk < 4; kk++) {
            bf16x8 B = wbv[(nt * 4 + kk) * 64 + lane];
            acc[nt] = __builtin_amdgcn_mfma_f32_16x16x32_bf16(A[kk], B, acc[nt], 0, 0, 0);
        }
    }
#pragma unroll
    for (int nt = 0; nt < 16; nt++) {
        int col = nt * 16 + m;
        if (nt < 8) {
            float bias = bl[col];
#pragma unroll
            for (int r = 0; r < 4; r++) {
                _Float16 hf = (_Float16)(acc[nt][r] + bias);
                xlh[(size_t)(row0 + q * 4 + r) * FDIM + col] = __builtin_bit_cast(ushort, hf);
            }
        } else {
            int c2 = col - 128;
            float bias = br[c2];
#pragma unroll
            for (int r = 0; r < 4; r++) {
                _Float16 hf = (_Float16)(acc[nt][r] + bias);
                xrh[(size_t)(row0 + q * 4 + r) * FDIM + c2] = __builtin_bit_cast(ushort, hf);
            }
        }
    }
}

// h = x @ Wp + bp (fp32 out), same structure, N=128 (8 tiles), no LN
__global__ __launch_bounds__(256) void proj_kernel(
        const float* __restrict__ x, const ushort* __restrict__ wb,
        const float* __restrict__ bp, float* __restrict__ h) {
    __shared__ uint4 fragbuf[4 * 272];
    int wid = (blockIdx.x * 256 + threadIdx.x) >> 6;
    int lane = threadIdx.x & 63;
    if (wid >= N_NODES / 16) return;
    uint4* fb = fragbuf + (threadIdx.x >> 6) * 272;
    int q = lane >> 4, m = lane & 15;
    int row0 = wid * 16;
    const float* xrow = x + (size_t)(row0 + m) * FDIM + q * 32;
#pragma unroll
    for (int p = 0; p < 4; p++) {
        float4 a = *(const float4*)&xrow[p * 8];
        float4 c = *(const float4*)&xrow[p * 8 + 4];
        uint4 u;
        u.x = pk_bf16(a.x, a.y); u.y = pk_bf16(a.z, a.w);
        u.z = pk_bf16(c.x, c.y); u.w = pk_bf16(c.z, c.w);
        fb[q * 68 + p * 17 + m] = u;
    }
    bf16x8 A[4];
#pragma unroll
    for (int kk = 0; kk < 4; kk++)
        A[kk] = *(const bf16x8*)&fb[kk * 68 + q * 17 + m];
    const bf16x8* wbv = (const bf16x8*)wb;
    f32x4 acc[8];
    f32x4 z = {0.f, 0.f, 0.f, 0.f};
#pragma unroll
    for (int nt = 0; nt < 8; nt++) acc[nt] = z;
#pragma unroll
    for (int nt = 0; nt < 8; nt++) {
#pragma unroll
        for (int kk = 0; kk < 4; kk++) {
            bf16x8 B = wbv[(nt * 4 + kk) * 64 + lane];
            acc[nt] = __builtin_amdgcn_mfma_f32_16x16x32_bf16(A[kk], B, acc[nt], 0, 0, 0);
        }
    }
#pragma unroll
    for (int nt = 0; nt < 8; nt++) {
        int col = nt * 16 + m;
        float bias = bp[col];
#pragma unroll
        for (int r = 0; r < 4; r++)
            h[(size_t)(row0 + q * 4 + r) * FDIM + col] = acc[nt][r] + bias;
    }
}

// classification = h @ Wc + bc, [N,128]@[128,16]
__global__ __launch_bounds__(256) void final_kernel(const float* __restrict__ h,
                                                    const float* __restrict__ Wc,
                                                    const float* __restrict__ bc,
                                                    float* __restrict__ out) {
    __shared__ float sh[16][128];
    int row0 = blockIdx.x * 16;
    int t = threadIdx.x;
    for (int i = t; i < 512; i += 256) {
        int r = i >> 5, c4 = (i & 31) * 4;
        *(float4*)&sh[r][c4] = *(const float4*)&h[(size_t)(row0 + r) * FDIM + c4];
    }
    __syncthreads();
    int m = t >> 4, k = t & 15;
    float acc = 0.f;
    for (int c = 0; c < 128; c += 4) {
        const float4 xv = *(const float4*)&sh[m][c];
        acc += xv.x * Wc[(c + 0) * NK + k] + xv.y * Wc[(c + 1) * NK + k]
             + xv.z * Wc[(c + 2) * NK + k] + xv.w * Wc[(c + 3) * NK + k];
    }
    out[(size_t)(row0 + m) * NK + k] = acc + bc[k];
}

// ---------------- GATv2 aggregation: one wave per node ----------------
// lane holds channels (2*lane, 2*lane+1) as ONE packed fp16 pair.
// Latency-focused: perm loaded as int4 kept in VGPRs and rfl'd only at USE
// (one block later) so index-load latency hides under compute; gathers issue
// 2 blocks ahead (c/d/e rotation); tail gathers prefetched in the prologue.
// Reduce + weight broadcasts are 100% DPP (quad_perm / row_ror) — the inner
// loop touches no LDS pipe at all. fp32 accumulate via v_fma_mix_f32.

__global__ __launch_bounds__(256) void gat_agg_kernel(
        const unsigned* __restrict__ xlp, const unsigned* __restrict__ xrp,
        const int* __restrict__ off, const int* __restrict__ perm,
        const float* __restrict__ att, const float* __restrict__ gb,
        float* __restrict__ h) {
    int wave = (blockIdx.x * 256 + threadIdx.x) >> 6;
    unsigned lane = threadIdx.x & 63;
    if (wave >= N_NODES) return;
    int i = wave;
    h2 xrv = as_h2(xrp[(unsigned)i * 64u + lane]);
    // hoist epilogue loads so their latency hides under the edge loop
    const float2 hid = *(const float2*)&h[(size_t)i * FDIM + lane * 2];
    const float2 gbv = *(const float2*)&gb[lane * 2];
    float2 attf = *(const float2*)&att[lane * 2];
    // fold ln2 rebase into att: exp(att.s) == exp2((att*log2e).s)
    h2 attp; attp[0] = (_Float16)(attf.x * 1.44269504f);
    attp[1] = (_Float16)(attf.y * 1.44269504f);
    const h2 c06 = {(_Float16)0.6f, (_Float16)0.6f};
    const h2 c04 = {(_Float16)0.4f, (_Float16)0.4f};
    bool b0 = lane & 1, b1 = lane & 2;
    int beg = __builtin_amdgcn_readfirstlane(off[i]);
    int end = __builtin_amdgcn_readfirstlane(off[i + 1]);
    float accx = 0.f, accy = 0.f, dloc = 0.f;
    const char* xlB = (const char*)xlp;
    unsigned laneB = lane << 2;

#define GLD(J) (*(const unsigned*)(xlB + ((unsigned)(J) * 256u + laneB)))

    // t = att . leaky(xl_j + xr_i) over this lane's 2 channels (log2 domain)
#define EDGE_PARTIAL(U, T)                                          \
    {                                                               \
        h2 mm = as_h2(U) + xrv;                                     \
        h2 am = as_h2(as_u(mm) & 0x7FFF7FFFu);                      \
        h2 sv = am * c04 + mm * c06;                                \
        T = __builtin_amdgcn_fdot2(sv, attp, 0.f, false);           \
    }

    // full 4-edge block: partials, select+butterfly + quad-rotate reduce
    // (all DPP), exp2, quad_perm weight broadcasts, 8 fma_mix accumulates
#define COMPUTE4(U0, U1, U2, U3)                                    \
    {                                                               \
        float t0, t1, t2, t3;                                       \
        EDGE_PARTIAL(U0, t0);                                       \
        EDGE_PARTIAL(U1, t1);                                       \
        EDGE_PARTIAL(U2, t2);                                       \
        EDGE_PARTIAL(U3, t3);                                       \
        float u   = b0 ? t1 : t0;                                   \
        float uu2 = b0 ? t0 : t1;                                   \
        u += DX1(uu2);                                              \
        float vv  = b0 ? t3 : t2;                                   \
        float vv2 = b0 ? t2 : t3;                                   \
        vv += DX1(vv2);                                             \
        float ww  = b1 ? vv : u;                                    \
        float ww2 = b1 ? u : vv;                                    \
        ww += DX2(ww2);                                             \
        ww += DR4(ww);                                              \
        ww += DR8(ww);                                              \
        float ew = exp2_hw(ww);                                     \
        dloc += ew;                                                 \
        float w0 = DB0(ew);                                         \
        float w1 = DB1(ew);                                         \
        float w2 = DB2(ew);                                         \
        float w3 = DB3(ew);                                         \
        FMAMIX_LO(accx, U0, w0); FMAMIX_HI(accy, U0, w0);           \
        FMAMIX_LO(accx, U1, w1); FMAMIX_HI(accy, U1, w1);           \
        FMAMIX_LO(accx, U2, w2); FMAMIX_HI(accy, U2, w2);           \
        FMAMIX_LO(accx, U3, w3); FMAMIX_HI(accy, U3, w3);           \
    }

    // single (tail) edge: full 16-lane reduce, weight uniform across row
#define TAIL1(U)                                                    \
    {                                                               \
        float tt;                                                   \
        EDGE_PARTIAL(U, tt);                                        \
        tt += DX1(tt);                                              \
        tt += DX2(tt);                                              \
        tt += DR4(tt);                                              \
        tt += DR8(tt);                                              \
        float w = exp2_hw(tt);                                      \
        if ((lane & 3) == 0) dloc += w;                             \
        FMAMIX_LO(accx, U, w); FMAMIX_HI(accy, U, w);               \
    }

    int nb = (end - beg) >> 2;          // full 4-edge blocks
    int tl = (end - beg) & 3;           // tail edges
    unsigned c0, c1, c2, c3, d0, d1, d2, d3;
    unsigned t0v = 0, t1v = 0, t2v = 0;
    int4 p2;                             // perm indices for block blk+2 (in flight)
    if (nb > 0) {
        int4 p0, p1;
        __builtin_memcpy(&p0, perm + beg, 16);
        __builtin_memcpy(&p1, perm + beg + 4, 16);
        __builtin_memcpy(&p2, perm + beg + 8, 16);
        c0 = GLD(rflm(p0.x)); c1 = GLD(rflm(p0.y)); c2 = GLD(rflm(p0.z)); c3 = GLD(rflm(p0.w));
        d0 = GLD(rflm(p1.x)); d1 = GLD(rflm(p1.y)); d2 = GLD(rflm(p1.z)); d3 = GLD(rflm(p1.w));
    }
    if (tl > 0) {
        int4 pt;
        __builtin_memcpy(&pt, perm + beg + 4 * nb, 16);
        t0v = GLD(rflm(pt.x));
        if (tl > 1) t1v = GLD(rflm(pt.y));
        if (tl > 2) t2v = GLD(rflm(pt.z));
    }
#pragma unroll 2
    for (int blk = 0; blk + 2 < nb; ++blk) {
        // issue block blk+2's gathers (indices prefetched one iteration ago)
        unsigned e0 = GLD(rflm(p2.x)), e1 = GLD(rflm(p2.y));
        unsigned e2 = GLD(rflm(p2.z)), e3 = GLD(rflm(p2.w));
        __builtin_memcpy(&p2, perm + beg + 4 * blk + 12, 16);   // block blk+3
        COMPUTE4(c0, c1, c2, c3);
        c0 = d0; c1 = d1; c2 = d2; c3 = d3;
        d0 = e0; d1 = e1; d2 = e2; d3 = e3;
    }
    if (nb >= 2) {
        COMPUTE4(c0, c1, c2, c3);
        c0 = d0; c1 = d1; c2 = d2; c3 = d3;
    }
    if (nb >= 1) COMPUTE4(c0, c1, c2, c3);
    if (tl > 0) {
        TAIL1(t0v);
        if (tl > 1) TAIL1(t1v);
        if (tl > 2) TAIL1(t2v);
    }
#undef EDGE_PARTIAL
#undef COMPUTE4
#undef TAIL1
#undef GLD

    // den = sum of dloc over the 4-lane subgroup (each edge counted once)
    float den = dloc + DX1(dloc);
    den += DX2(den);
    float inv = 1.f / den;
    float ox = accx * inv + gbv.x;
    float oy = accy * inv + gbv.y;
    float2 res;
    res.x = fmaxf(ox, 0.f) + hid.x;
    res.y = fmaxf(oy, 0.f) + hid.y;
    *(float2*)&h[(size_t)i * FDIM + lane * 2] = res;
}

// ---------------- launch ----------------

extern "C" void kernel_launch(void* const* d_in, const int* in_sizes, int n_in,
                              void* d_out, int out_size, void* d_ws, size_t ws_size,
                              hipStream_t stream) {
    const float* x    = (const float*)d_in[0];
    const int*   ei   = (const int*)  d_in[1];
    const float* Wp   = (const float*)d_in[2];
    const float* bp   = (const float*)d_in[3];
    const float* ln_g = (const float*)d_in[4];
    const float* ln_b = (const float*)d_in[5];
    const float* Wl   = (const float*)d_in[6];
    const float* bl   = (const float*)d_in[7];
    const float* Wr   = (const float*)d_in[8];
    const float* br   = (const float*)d_in[9];
    const float* att  = (const float*)d_in[10];
    const float* gb   = (const float*)d_in[11];
    const float* Wc   = (const float*)d_in[12];
    const float* bc   = (const float*)d_in[13];

    float* out_cls = (float*)d_out;
    float* h = out_cls + (size_t)N_NODES * NK;   // second output region doubles as h buffer

    char* w = (char*)d_ws;
    int* off    = (int*)w; w += (size_t)(N_NODES + 1) * sizeof(int);
    int* gcount = (int*)w; w += 256 * sizeof(int);
    int* perm   = (int*)w; w += (size_t)ET * sizeof(int);
    uintptr_t a = ((uintptr_t)w + 255) & ~(uintptr_t)255;
    ushort* xlh = (ushort*)a;                             // [N][128] fp16
    ushort* xrh = xlh + (size_t)N_NODES * FDIM;           // [N][128] fp16
    ushort* wbp = xrh + (size_t)N_NODES * FDIM;             // proj W swizzled (32 KB)
    ushort* wbl0 = wbp + 8 * 4 * 64 * 8;                    // layer0 Wl|Wr (64 KB)
    ushort* wbl1 = wbl0 + 16 * 4 * 64 * 8;                  // layer1
    int* staging = (int*)xlh;   // phase-1 staging aliases xlh (8 MB; dead before ln_gemm2)

    // W swizzles (one launch for all three targets)
    swizzle_kernel<<<40, 256, 0, stream>>>(Wp, Wl, Wr, wbp, wbl0, wbl1);

    // CSR by dst (rebuilt every call — ws is re-poisoned)
    hipMemsetAsync(gcount, 0, NBKT * sizeof(int), stream);
    part_kernel<<<(ET + P1_EPB - 1) / P1_EPB, 256, 0, stream>>>(ei, gcount, staging);
    bucket_csr_kernel<<<NBKT, 1024, 0, stream>>>(staging, gcount, off, perm);

    const int gw = (N_NODES / 16 + 3) / 4;   // 1563 blocks (4 waves/block, 16 rows/wave)
    proj_kernel<<<gw, 256, 0, stream>>>(x, wbp, bp, h);

    for (int l = 0; l < 2; ++l) {
        ln_gemm2_kernel<<<gw, 256, 0, stream>>>(
            h, ln_g + l * FDIM, ln_b + l * FDIM,
            (l == 0) ? wbl0 : wbl1, bl + l * FDIM, br + l * FDIM,
            xlh, xrh);
        gat_agg_kernel<<<N_NODES / 4, 256, 0, stream>>>(
            (const unsigned*)xlh, (const unsigned*)xrh, off, perm,
            att + l * FDIM, gb + l * FDIM, h);
    }

    final_kernel<<<N_NODES / 16, 256, 0, stream>>>(h, Wc, bc, out_cls);
}